// Round 13
// baseline (1589.102 us; speedup 1.0000x reference)
//
#include <hip/hip_runtime.h>
#include <cstdint>
#include <cmath>
#include <cstddef>

// ---------------- problem constants ----------------
constexpr int NN   = 1024;     // nodes
constexpr int NE   = 16384;    // edges
constexpr int HSZ  = 128;      // hidden size
constexpr int NSH  = 25;       // spherical harmonics (l<=4)
constexpr int NRBF = 32;
constexpr int NLAY = 5;
constexpr int XSZ  = HSZ * NSH;   // 3200
constexpr int HII_SZ = NN * 196;  // 200704
constexpr int TKP  = 800;         // padded Tk row: 25 i-rows x 32 slots

// x/agg/att layout: [n][m][c]  (element (n,m,c) at n*3200 + m*128 + c)

// ---------------- ws layout (float offsets) ----------------
constexpr size_t OFF_CONSTS = 0;  // CG 15625 | EXP 4900 | logbinom 32  (20557, pad 20560)
constexpr size_t OFF_X    = 20560;
constexpr size_t OFF_AGG  = OFF_X    + (size_t)NN * XSZ;
constexpr size_t OFF_ATT  = OFF_AGG  + (size_t)NN * XSZ;
constexpr size_t OFF_X0   = OFF_ATT  + (size_t)NN * XSZ;
constexpr size_t OFF_NSC  = OFF_X0   + (size_t)NN * HSZ;
constexpr size_t OFF_Q    = OFF_NSC  + (size_t)NN * HSZ;
constexpr size_t OFF_K    = OFF_Q    + (size_t)NN * HSZ;
constexpr size_t OFF_RBF  = OFF_K    + (size_t)NN * HSZ;
constexpr size_t OFF_SH   = OFF_RBF  + (size_t)NE * NRBF;
constexpr size_t OFF_TK   = OFF_SH   + (size_t)NE * NSH;
constexpr size_t OFF_WRAD = OFF_TK   + (size_t)NE * TKP;   // padded Tk
constexpr size_t OFF_AGG2 = OFF_WRAD + (size_t)NE * HSZ;   // chunk-1 partials
constexpr size_t OFF_ATT2 = OFF_AGG2 + (size_t)NN * XSZ;
constexpr size_t OFF_INT  = OFF_ATT2 + (size_t)NN * XSZ;   // ints start here
constexpr size_t NEED_BYTES = OFF_INT * 4 + (size_t)(1024 + 1025 + 1024 + 16384) * 4;
// aliases: logits->OFF_SH (65536) | alpha->OFF_SH+65536 | fm->OFF_AGG | awb->OFF_AGG+819200

// =====================================================================
// Host-side reproduction of np.random.default_rng(7) (verified round 3).
// =====================================================================
namespace qhc {

struct Pcg64 {
  unsigned __int128 state, inc;
  static unsigned __int128 mult() {
    return (((unsigned __int128)2549297995355413924ULL) << 64) | 4865540595714422341ULL;
  }
  void step() { state = state * mult() + inc; }
  uint64_t next64() {
    step();
    uint64_t hi = (uint64_t)(state >> 64), lo = (uint64_t)state;
    uint64_t x = hi ^ lo;
    unsigned rot = (unsigned)(state >> 122);
    return (x >> rot) | (x << ((64u - rot) & 63u));
  }
  double nextd() { return (double)(next64() >> 11) * (1.0 / 9007199254740992.0); }
};

struct HostConsts {
  float buf[20560];
  HostConsts() {
    const uint32_t INIT_A = 0x43b0d7e5u, MULT_A = 0x931e8875u;
    const uint32_t INIT_B = 0x8b51f9ddu, MULT_B = 0x58f38dedu;
    uint32_t pool[4];
    uint32_t hc = INIT_A;
    auto hashf = [&](uint32_t v) -> uint32_t {
      v ^= hc; hc *= MULT_A; v *= hc; v ^= v >> 16; return v;
    };
    auto mixf = [](uint32_t x, uint32_t y) -> uint32_t {
      uint32_t r = x * 0xca01f9ddu - y * 0x4973f715u;
      r ^= r >> 16;
      return r;
    };
    pool[0] = hashf(7u);
    for (int i = 1; i < 4; i++) pool[i] = hashf(0u);
    for (int s = 0; s < 4; s++)
      for (int d = 0; d < 4; d++)
        if (s != d) pool[d] = mixf(pool[d], hashf(pool[s]));
    uint32_t st32[8];
    uint32_t hb = INIT_B;
    for (int i = 0; i < 8; i++) {
      uint32_t v = pool[i % 4];
      v ^= hb; hb *= MULT_B; v *= hb; v ^= v >> 16;
      st32[i] = v;
    }
    uint64_t w0 = st32[0] | ((uint64_t)st32[1] << 32);
    uint64_t w1 = st32[2] | ((uint64_t)st32[3] << 32);
    uint64_t w2 = st32[4] | ((uint64_t)st32[5] << 32);
    uint64_t w3 = st32[6] | ((uint64_t)st32[7] << 32);
    unsigned __int128 seed = (((unsigned __int128)w0) << 64) | w1;
    unsigned __int128 incs = (((unsigned __int128)w2) << 64) | w3;
    Pcg64 g;
    g.state = 0; g.inc = (incs << 1) | 1;
    g.step(); g.state += seed; g.step();
    double wi[256], fi[256]; uint64_t ki[256];
    {
      const double m1 = 4503599627370496.0;
      double dn = 3.6541528853610087963519472518, tn = dn, vn = 0.00492867323399941;
      double q = vn / std::exp(-0.5 * dn * dn);
      ki[0] = (uint64_t)((dn / q) * m1); ki[1] = 0;
      wi[0] = q / m1; wi[255] = dn / m1;
      fi[0] = 1.0; fi[255] = std::exp(-0.5 * dn * dn);
      for (int i = 254; i >= 1; i--) {
        dn = std::sqrt(-2.0 * std::log(vn / dn + std::exp(-0.5 * dn * dn)));
        ki[i + 1] = (uint64_t)((dn / tn) * m1);
        tn = dn;
        fi[i] = std::exp(-0.5 * dn * dn);
        wi[i] = dn / m1;
      }
    }
    const double ZR = 3.6541528853610087963519472518;
    const double ZIR = 0.27366123732975827203338247596;
    auto stdnorm = [&]() -> double {
      for (;;) {
        uint64_t r = g.next64();
        int idx = (int)(r & 0xff);
        r >>= 8;
        int sign = (int)(r & 1);
        uint64_t rabs = (r >> 1) & 0x000fffffffffffffULL;
        double xv = (double)rabs * wi[idx];
        if (sign) xv = -xv;
        if (rabs < ki[idx]) return xv;
        if (idx == 0) {
          for (;;) {
            double xx = -ZIR * std::log1p(-g.nextd());
            double yy = -std::log1p(-g.nextd());
            if (yy + yy > xx * xx)
              return ((rabs >> 8) & 1) ? -(ZR + xx) : (ZR + xx);
          }
        } else {
          if (((fi[idx - 1] - fi[idx]) * g.nextd() + fi[idx]) < std::exp(-0.5 * xv * xv))
            return xv;
        }
      }
    };
    for (int i = 0; i < 15625 + 4900; i++) buf[i] = (float)(0.1 * stdnorm());
    double logf[32]; logf[0] = 0.0;
    for (int i = 1; i < 32; i++) logf[i] = logf[i - 1] + std::log((double)i);
    for (int k = 0; k < 32; k++) buf[15625 + 4900 + k] = (float)(logf[31] - logf[k] - logf[31 - k]);
    buf[20557] = buf[20558] = buf[20559] = 0.f;
  }
};
static HostConsts g_hc;
}  // namespace qhc

// =====================================================================
__device__ __forceinline__ float siluf(float a) { return a / (1.f + expf(-a)); }

// ---------------- edge geometry: sh + rbf ----------------
__global__ __launch_bounds__(256) void qh_geom(
    const float* __restrict__ pos, const int* __restrict__ ei,
    const float* __restrict__ lbn, float* __restrict__ rbf, float* __restrict__ sh) {
  int e = blockIdx.x * 256 + threadIdx.x;
  if (e >= NE) return;
  int s = ei[e], d = ei[NE + e];
  float vx = pos[s * 3 + 0] - pos[d * 3 + 0];
  float vy = pos[s * 3 + 1] - pos[d * 3 + 1];
  float vz = pos[s * 3 + 2] - pos[d * 3 + 2];
  float r = sqrtf(vx * vx + vy * vy + vz * vz + 1e-12f);
  float inv = 1.0f / r;
  float x = vx * inv, y = vy * inv, z = vz * inv;
  float x2 = x * x, y2 = y * y, z2 = z * z;
  float* sp = sh + (size_t)e * NSH;
  sp[0] = 0.282095f;
  sp[1] = 0.488603f * y;
  sp[2] = 0.488603f * z;
  sp[3] = 0.488603f * x;
  sp[4] = 1.092548f * x * y;
  sp[5] = 1.092548f * y * z;
  sp[6] = 0.315392f * (3.f * z2 - 1.f);
  sp[7] = 1.092548f * x * z;
  sp[8] = 0.546274f * (x2 - y2);
  sp[9] = 0.590044f * y * (3.f * x2 - y2);
  sp[10] = 2.890611f * x * y * z;
  sp[11] = 0.457046f * y * (5.f * z2 - 1.f);
  sp[12] = 0.373176f * z * (5.f * z2 - 3.f);
  sp[13] = 0.457046f * x * (5.f * z2 - 1.f);
  sp[14] = 1.445306f * z * (x2 - y2);
  sp[15] = 0.590044f * x * (x2 - 3.f * y2);
  sp[16] = 2.503343f * x * y * (x2 - y2);
  sp[17] = 1.770131f * y * z * (3.f * x2 - y2);
  sp[18] = 0.946175f * x * y * (7.f * z2 - 1.f);
  sp[19] = 0.669047f * y * z * (7.f * z2 - 3.f);
  sp[20] = 0.105786f * (35.f * z2 * z2 - 30.f * z2 + 3.f);
  sp[21] = 0.669047f * x * z * (7.f * z2 - 3.f);
  sp[22] = 0.473087f * (x2 - y2) * (7.f * z2 - 1.f);
  sp[23] = 1.770131f * x * z * (x2 - 3.f * y2);
  sp[24] = 0.625836f * (x2 * x2 - 6.f * x2 * y2 + y2 * y2);
  float xr = expf(-0.5f * r);
  float l1 = log1pf(-xr + 1e-7f);
  float fc = 0.5f * (cosf(3.14159265358979323846f * fminf(r * (1.0f / 12.0f), 1.0f)) + 1.0f);
  float* rp = rbf + (size_t)e * NRBF;
  for (int k = 0; k < NRBF; k++) {
    float b = expf(lbn[k] + (float)k * (-0.5f * r) + (float)(NRBF - 1 - k) * l1);
    rp[k] = b * fc;
  }
}

// ---------------- Tkp[e][i][32] (padded, wave-group-aligned) ----------------
__global__ __launch_bounds__(256) void qh_tk(
    const float* __restrict__ sh, const float* __restrict__ CG, float* __restrict__ Tkp) {
  __shared__ float shl[32 * NSH];
  int e0 = blockIdx.x * 32;
  int t = threadIdx.x;
  for (int i = t; i < 32 * NSH; i += 256) shl[i] = sh[(size_t)e0 * NSH + i];
  // zero all slots; value slots overwritten after the barrier
  for (int i = t; i < 32 * TKP; i += 256) Tkp[(size_t)e0 * TKP + i] = 0.f;
  __syncthreads();
  for (int ik = t; ik < NSH * NSH; ik += 256) {
    int i = ik / NSH, k = ik % NSH;
    int pos = i * 32 + k + (k >= 7) + 2 * (k >= 13) + 2 * (k >= 19);
    float cg[NSH];
#pragma unroll
    for (int j = 0; j < NSH; j++) cg[j] = CG[i * 625 + j * NSH + k];
    for (int ee = 0; ee < 32; ee++) {
      float acc = 0.f;
#pragma unroll
      for (int j = 0; j < NSH; j++) acc += shl[ee * NSH + j] * cg[j];
      Tkp[(size_t)(e0 + ee) * TKP + pos] = acc;
    }
  }
}

// ---------------- node scalar MLP + init x ([m][c] layout) ----------------
__global__ __launch_bounds__(128) void qh_nsc(
    const int* __restrict__ z, const int* __restrict__ tptr, const int* __restrict__ sptr,
    const float* __restrict__ embed, const float* __restrict__ tT, const float* __restrict__ tH,
    const float* __restrict__ W1, const float* __restrict__ b1,
    const float* __restrict__ W2, const float* __restrict__ b2,
    float* __restrict__ nsc, float* __restrict__ x, float* __restrict__ x0) {
  __shared__ float cat[384];
  __shared__ float h[128];
  int nd = blockIdx.x, d = threadIdx.x;
  int zz = z[nd], tt = tptr[0], st = sptr[0];
  cat[d] = embed[zz * HSZ + d];
  cat[128 + d] = tT[tt * HSZ + d];
  cat[256 + d] = tH[st * HSZ + d];
  __syncthreads();
  float a = b1[d];
  for (int c = 0; c < 384; c++) a += cat[c] * W1[c * HSZ + d];
  h[d] = fmaxf(a, 0.f);
  __syncthreads();
  a = b2[d];
  for (int c = 0; c < 128; c++) a += h[c] * W2[c * HSZ + d];
  nsc[nd * HSZ + d] = a;
  x0[nd * HSZ + d] = a;
  float* xr = x + (size_t)nd * XSZ + d;
  xr[0] = a;                       // m=0
  for (int m = 1; m < NSH; m++) xr[m * 128] = 0.f;
}

// ---------------- dst-bucket sort ----------------
__global__ __launch_bounds__(256) void qh_zero(int* counts) {
  int i = blockIdx.x * 256 + threadIdx.x;
  if (i < NN) counts[i] = 0;
}
__global__ __launch_bounds__(256) void qh_count(const int* __restrict__ ei, int* counts) {
  int e = blockIdx.x * 256 + threadIdx.x;
  if (e < NE) atomicAdd(&counts[ei[NE + e]], 1);
}
__global__ __launch_bounds__(1024) void qh_scan(const int* __restrict__ counts,
                                                int* starts, int* cursor) {
  __shared__ int tmp[NN];
  int t = threadIdx.x;
  tmp[t] = counts[t];
  __syncthreads();
  for (int ofs = 1; ofs < NN; ofs <<= 1) {
    int v = (t >= ofs) ? tmp[t - ofs] : 0;
    __syncthreads();
    tmp[t] += v;
    __syncthreads();
  }
  starts[t + 1] = tmp[t];
  if (t == 0) starts[0] = 0;
  cursor[t] = (t == 0) ? 0 : tmp[t - 1];
}
__global__ __launch_bounds__(256) void qh_scatter(const int* __restrict__ ei,
                                                  int* cursor, int* perm) {
  int e = blockIdx.x * 256 + threadIdx.x;
  if (e < NE) {
    int d = ei[NE + e];
    int pos = atomicAdd(&cursor[d], 1);
    perm[pos] = e;
  }
}

// ---------------- radial MLP: 16 edges/block, 4-edge-parallel phases ----------------
__global__ __launch_bounds__(256) void qh_rad(
    const float* __restrict__ rbf,
    const float* __restrict__ W1, const float* __restrict__ b1,
    const float* __restrict__ W2, const float* __restrict__ b2,
    const float* __restrict__ W3, const float* __restrict__ b3,
    float* __restrict__ wrad) {
  __shared__ float w1l[2048], w2l[4096], w3l[8192];
  __shared__ float rl[4][32], h1[4][64], h2[4][64];
  int t = threadIdx.x;
  for (int i = t; i < 2048; i += 256) w1l[i] = W1[i];
  for (int i = t; i < 4096; i += 256) w2l[i] = W2[i];
  for (int i = t; i < 8192; i += 256) w3l[i] = W3[i];
  __syncthreads();
  int e0 = blockIdx.x * 16;
  for (int q = 0; q < 4; q++) {
    int eb = e0 + q * 4;
    if (t < 128) rl[t >> 5][t & 31] = rbf[(size_t)(eb + (t >> 5)) * NRBF + (t & 31)];
    __syncthreads();
    {
      int eg = t >> 6, u = t & 63;
      float a = b1[u];
      for (int c = 0; c < 32; c++) a += rl[eg][c] * w1l[c * 64 + u];
      h1[eg][u] = siluf(a);
    }
    __syncthreads();
    {
      int eg = t >> 6, u = t & 63;
      float a = b2[u];
      for (int c = 0; c < 64; c++) a += h1[eg][c] * w2l[c * 64 + u];
      h2[eg][u] = siluf(a);
    }
    __syncthreads();
#pragma unroll
    for (int p = 0; p < 2; p++) {
      int eg = (t >> 7) + p * 2, u = t & 127;
      float a = b3[u];
      for (int c = 0; c < 64; c++) a += h2[eg][c] * w3l[c * 128 + u];
      wrad[(size_t)(eb + eg) * HSZ + u] = a;
    }
    __syncthreads();
  }
}

// ---------------- q/k projections ----------------
__global__ __launch_bounds__(256) void qh_qk(
    const float* __restrict__ x0, const float* __restrict__ Wq, const float* __restrict__ Wk,
    float* __restrict__ q, float* __restrict__ kk) {
  __shared__ float xl[128];
  int nd = blockIdx.x, t = threadIdx.x;
  if (t < 128) xl[t] = x0[nd * HSZ + t];
  __syncthreads();
  int d = t & 127;
  const float* W = (t < 128) ? Wq : Wk;
  float a = 0.f;
  for (int c = 0; c < 128; c++) a += xl[c] * W[c * HSZ + d];
  if (t < 128) q[nd * HSZ + d] = a;
  else kk[nd * HSZ + d] = a;
}

// ---------------- edge-parallel attention logits ----------------
__global__ __launch_bounds__(256) void qh_logit(
    const float* __restrict__ q, const float* __restrict__ kk,
    const int* __restrict__ ei, float* __restrict__ logits) {
  int t = threadIdx.x;
  int e = blockIdx.x * 2 + (t >> 7);
  int c = t & 127;
  int s = ei[e], d = ei[NE + e];
  float p = q[d * HSZ + c] * kk[s * HSZ + c];
#pragma unroll
  for (int m = 16; m >= 1; m >>= 1) p += __shfl_xor(p, m);
  if ((c & 31) == 0) logits[e * 4 + (c >> 5)] = p * 0.17677669529663687f;
}

// ---------------- per-node exact softmax (16 lanes per head) ----------------
__global__ __launch_bounds__(64) void qh_soft(
    const float* __restrict__ logits, const int* __restrict__ starts,
    const int* __restrict__ perm, float* __restrict__ alpha) {
  int nd = blockIdx.x, t = threadIdx.x;
  int hh = t >> 4, l = t & 15;
  int jb = starts[nd], je = starts[nd + 1];
  float m = -1e30f;
  for (int j = jb + l; j < je; j += 16) m = fmaxf(m, logits[perm[j] * 4 + hh]);
#pragma unroll
  for (int s = 1; s < 16; s <<= 1) m = fmaxf(m, __shfl_xor(m, s));
  float den = 0.f;
  for (int j = jb + l; j < je; j += 16) den += expf(logits[perm[j] * 4 + hh] - m);
#pragma unroll
  for (int s = 1; s < 16; s <<= 1) den += __shfl_xor(den, s);
  float inv = 1.f / (den + 1e-9f);
  for (int j = jb + l; j < je; j += 16) {
    int e = perm[j];
    alpha[e * 4 + hh] = expf(logits[e * 4 + hh] - m) * inv;
  }
}

// ---------------- fused message + attention agg (2-chunk split vs bucket tail) ----
// r12 counters: 8 blocks/CU all co-resident, occupancy 54% => wall set by the
// max-degree bucket (Poisson(16), max ~33 over 1024 nodes; tail blocks do ~2x
// mean work while half the machine idles). Split each (node,half) bucket into
// TWO chunks (grid NN*4): chunk 0 = first ceil(cnt/2) edges -> agg/att,
// chunk 1 = rest -> agg2/att2 (zeros when empty). Max chunk ~17 edges ==
// balance limit (total work / 2048 slots = 16). mix is linear => mixgemm
// stages Al = agg+agg2; gate adds att2. Swizzle keeps all 4 blocks of a node
// on one XCD: nd=(bid>>5)*8+(bid&7), h=(bid>>3)&1, ch=(bid>>4)&1 (bijective).
__global__ __launch_bounds__(256, 8) void qh_msgatt(
    const float* __restrict__ x, const float* __restrict__ Tkp,
    const float* __restrict__ wrad, const float* __restrict__ alpha,
    const int* __restrict__ starts, const int* __restrict__ perm,
    const int* __restrict__ ei,
    float* __restrict__ agg, float* __restrict__ att,
    float* __restrict__ agg2, float* __restrict__ att2) {
  __shared__ __align__(16) float xs[2][1600];   // [m][cl] 25 x 64
  __shared__ float wl[2][64];
  int bid = blockIdx.x;
  int nd = (bid >> 5) * 8 + (bid & 7);          // XCD-pairing swizzle
  int h  = (bid >> 3) & 1;
  int ch = (bid >> 4) & 1;
  int t = threadIdx.x;
  int cl = t & 63, q4 = t >> 6;
  int q4u = __builtin_amdgcn_readfirstlane(q4);   // wave id -> SGPR
  int c = h * 64 + cl;
  int k0 = (q4 == 0) ? 0 : (1 + 6 * q4); // {0,7,13,19}
  int nk = (q4 == 0) ? 7 : 6;
  float am[7], aa[7];
#pragma unroll
  for (int u = 0; u < 7; u++) { am[u] = 0.f; aa[u] = 0.f; }
  int jb = starts[nd], je = starts[nd + 1];
  int cnt = je - jb;
  int half1 = (cnt + 1) >> 1;                   // chunk 0 size
  int cb = ch ? (jb + half1) : jb;              // this chunk's range
  int ce = ch ? je : (jb + half1);

  float4 rxA = {0, 0, 0, 0}, rxB = {0, 0, 0, 0};
  float rw = 0.f;
  if (cb < ce) {
    int e = perm[cb], s = ei[e];
    const float* xb0 = x + (size_t)s * XSZ + h * 64;
    rxA = *(const float4*)(xb0 + (t >> 4) * 128 + (t & 15) * 4);
    if (t < 144) rxB = *(const float4*)(xb0 + ((256 + t) >> 4) * 128 + (t & 15) * 4);
    if (t < 64) rw = wrad[(size_t)e * HSZ + h * 64 + t];
    ((float4*)xs[0])[t] = rxA;
    if (t < 144) ((float4*)xs[0])[256 + t] = rxB;
    if (t < 64) wl[0][t] = rw;
  }
  __syncthreads();
  for (int j = cb; j < ce; j++) {
    int cur = (j - cb) & 1, nxt = cur ^ 1;
    int e = perm[j];
    int eu = __builtin_amdgcn_readfirstlane(e);   // uniform edge id -> SGPR
    const float* tkr = Tkp + (size_t)eu * TKP + q4u * 8;  // all-scalar address
    float al = alpha[e * 4 + (c >> 5)];
    bool more = (j + 1 < ce);
    if (more) {  // register prefetch of next edge's x/wrad overlaps compute
      int e2 = perm[j + 1], s2 = ei[e2];
      const float* xb2 = x + (size_t)s2 * XSZ + h * 64;
      rxA = *(const float4*)(xb2 + (t >> 4) * 128 + (t & 15) * 4);
      if (t < 144) rxB = *(const float4*)(xb2 + ((256 + t) >> 4) * 128 + (t & 15) * 4);
      if (t < 64) rw = wrad[(size_t)e2 * HSZ + h * 64 + t];
    }
    float wc = wl[cur][cl];
#pragma unroll 5
    for (int i = 0; i < NSH; i++) {
      float xw = xs[cur][i * 64 + cl] * wc;
      float4 t0 = *(const float4*)(tkr + i * 32);       // wave-uniform 16B
      float4 t1 = *(const float4*)(tkr + i * 32 + 4);   // wave-uniform 16B
      am[0] += xw * t0.x; am[1] += xw * t0.y; am[2] += xw * t0.z; am[3] += xw * t0.w;
      am[4] += xw * t1.x; am[5] += xw * t1.y; am[6] += xw * t1.z;
    }
#pragma unroll
    for (int u = 0; u < 7; u++)
      if (u < nk) aa[u] += al * xs[cur][(k0 + u) * 64 + cl];
    __syncthreads();
    if (more) {
      ((float4*)xs[nxt])[t] = rxA;
      if (t < 144) ((float4*)xs[nxt])[256 + t] = rxB;
      if (t < 64) wl[nxt][t] = rw;
    }
    __syncthreads();
  }
  float* ga = ch ? agg2 : agg;
  float* ta = ch ? att2 : att;
#pragma unroll
  for (int u = 0; u < 7; u++)
    if (u < nk) {
      ga[(size_t)nd * XSZ + (k0 + u) * 128 + c] = am[u];
      ta[(size_t)nd * XSZ + (k0 + u) * 128 + c] = aa[u];
    }
}

// ---------------- mix as row-GEMM: agg <- (agg+agg2) @ W_lb (in place) ------------
// 800 blocks: per-lb row tiles of 32 (rows exclusive per block -> in-place safe).
// Al = agg + agg2 (chunk partials summed during staging; mix is linear).
__global__ __launch_bounds__(256) void qh_mixgemm(
    const float* __restrict__ mixW, float* __restrict__ agg,
    const float* __restrict__ agg2) {
  __shared__ __align__(16) float Wl[16384];  // [cc][128], 64 KB
  __shared__ __align__(16) float Al[4096];   // [32 rows][128 cc], 16 KB
  int b = blockIdx.x, t = threadIdx.x;
  int lb, cum;
  if (b < 32)       { lb = 0; cum = 0; }
  else if (b < 128) { lb = 1; cum = 32; }
  else if (b < 288) { lb = 2; cum = 128; }
  else if (b < 512) { lb = 3; cum = 288; }
  else              { lb = 4; cum = 512; }
  int sl = 2 * lb + 1, o = lb * lb;
  int row0 = (b - cum) * 32;
  const float* W = mixW + lb * 16384;
  // Al staging: 1024 float4 (each row is 32 float4s), summing both chunks
  for (int i = t; i < 1024; i += 256) {
    int r = i >> 5, c4 = (i & 31) * 4;
    int gr = row0 + r, n = gr / sl, m = o + gr - n * sl;
    size_t idx = (size_t)n * XSZ + m * 128 + c4;
    float4 a = *(const float4*)&agg[idx];
    float4 b4 = *(const float4*)&agg2[idx];
    float4 v; v.x = a.x + b4.x; v.y = a.y + b4.y; v.z = a.z + b4.z; v.w = a.w + b4.w;
    *(float4*)&Al[r * 128 + c4] = v;
  }
  // Wl staging: linear copy of the whole [128][128] tile (4096 float4)
  for (int i = t; i < 4096; i += 256)
    *(float4*)&Wl[i * 4] = *(const float4*)&W[i * 4];
  __syncthreads();
  int d4 = (t & 31) * 4;   // 4 consecutive d
  int rg = t >> 5;         // 8 groups x 4 rows
  float acc[4][4];
#pragma unroll
  for (int r = 0; r < 4; r++)
#pragma unroll
    for (int q = 0; q < 4; q++) acc[r][q] = 0.f;
  for (int cc = 0; cc < 128; cc++) {
    float4 w4 = *(const float4*)&Wl[cc * 128 + d4];
#pragma unroll
    for (int r = 0; r < 4; r++) {
      float a = Al[(rg * 4 + r) * 128 + cc];
      acc[r][0] += a * w4.x; acc[r][1] += a * w4.y;
      acc[r][2] += a * w4.z; acc[r][3] += a * w4.w;
    }
  }
#pragma unroll
  for (int r = 0; r < 4; r++) {
    int gr = row0 + rg * 4 + r, n = gr / sl, m = o + gr - n * sl;
    float4 v; v.x = acc[r][0]; v.y = acc[r][1]; v.z = acc[r][2]; v.w = acc[r][3];
    *(float4*)&agg[(size_t)n * XSZ + m * 128 + d4] = v;
  }
}

// ---------------- gate epilogue: x = gate(x + y + att + att2) ----------------
__global__ __launch_bounds__(256) void qh_gate(
    const float* __restrict__ y, const float* __restrict__ att,
    const float* __restrict__ att2,
    float* __restrict__ x, float* __restrict__ x0) {
  __shared__ float v0l[128];
  int nd = blockIdx.x, t = threadIdx.x;
  int d = t & 127, mh = t >> 7;
  int m0 = mh ? 13 : 0, nm = mh ? 12 : 13;
  float v[13];
  size_t base = (size_t)nd * XSZ + (size_t)m0 * 128 + d;
#pragma unroll
  for (int u = 0; u < 13; u++)
    if (u < nm) v[u] = x[base + (size_t)u * 128] + y[base + (size_t)u * 128]
                     + att[base + (size_t)u * 128] + att2[base + (size_t)u * 128];
  if (mh == 0) v0l[d] = v[0];
  __syncthreads();
  float g = 1.f / (1.f + expf(-v0l[d]));
#pragma unroll
  for (int u = 0; u < 13; u++)
    if (u < nm) x[base + (size_t)u * 128] = v[u] * g;   // m=0: v0*g == silu(v0)
  if (mh == 0) x0[nd * HSZ + d] = v[0] * g;
}

// ---------------- per-node output precompute + H_ii ----------------
__global__ __launch_bounds__(256) void qh_prep(
    const float* __restrict__ x, const float* __restrict__ nsc,
    const float* __restrict__ Wii, const float* __restrict__ Wij,
    const float* __restrict__ pii, const float* __restrict__ pij,
    const float* __restrict__ EXPc,
    float* __restrict__ fm, float* __restrict__ awb, float* __restrict__ out) {
  __shared__ float xl[XSZ];
  __shared__ float nl[128];
  __shared__ float wc[4096];
  __shared__ float fml[800];
  __shared__ float wiil[32];
  __shared__ float gl[25];
  int nd = blockIdx.x, t = threadIdx.x;
  for (int i = t; i < XSZ; i += 256) xl[i] = x[(size_t)nd * XSZ + i];
  if (t < 128) nl[t] = nsc[nd * HSZ + t];
  __syncthreads();
  if (t < 32) {
    float a = 0.f;
    for (int cc = 0; cc < 128; cc++) a += nl[cc] * pii[cc * 32 + t];
    wiil[t] = a;
  } else if (t < 96) {
    int d = (t - 32) & 31;
    int half = (t - 32) >> 5;
    const float* pp = pij + (half ? 128 * 32 : 0);
    float a = 0.f;
    for (int cc = 0; cc < 128; cc++) a += nl[cc] * pp[cc * 32 + d];
    awb[nd * 64 + half * 32 + d] = a;
  }
  for (int lb = 0; lb < 5; lb++) {
    __syncthreads();
    for (int i = t; i < 4096; i += 256) wc[i] = Wii[lb * 4096 + i];
    __syncthreads();
    int o = lb * lb, sl = 2 * lb + 1;
    for (int idx = t; idx < 32 * sl; idx += 256) {
      int d = idx & 31, m = o + (idx >> 5);
      float a = 0.f;
      for (int cc = 0; cc < 128; cc++) a += xl[m * 128 + cc] * wc[cc * 32 + d];
      fml[d * NSH + m] = a;
    }
  }
  __syncthreads();
  if (t < 25) {
    float a = 0.f;
#pragma unroll
    for (int d = 0; d < 32; d++) a += wiil[d] * fml[d * NSH + t];
    gl[t] = a;
  }
  __syncthreads();
  if (t < 196) {
    float a = 0.f;
#pragma unroll
    for (int m = 0; m < 25; m++) a += gl[m] * EXPc[m * 196 + t];
    out[(size_t)nd * 196 + t] = a;
  }
  for (int lb = 0; lb < 5; lb++) {
    __syncthreads();
    for (int i = t; i < 4096; i += 256) wc[i] = Wij[lb * 4096 + i];
    __syncthreads();
    int o = lb * lb, sl = 2 * lb + 1;
    for (int idx = t; idx < 32 * sl; idx += 256) {
      int d = idx & 31, m = o + (idx >> 5);
      float a = 0.f;
      for (int cc = 0; cc < 128; cc++) a += xl[m * 128 + cc] * wc[cc * 32 + d];
      fm[(size_t)nd * 800 + d * NSH + m] = a;
    }
  }
}

// ---------------- H_ij per edge (factorized) ----------------
__global__ __launch_bounds__(256) void qh_fij2(
    const int* __restrict__ ei, const float* __restrict__ fm,
    const float* __restrict__ awb, const float* __restrict__ EXPc,
    float* __restrict__ out) {
  __shared__ float fsum[800], wsum[32], gl[25];
  int e = blockIdx.x, t = threadIdx.x;
  int s = ei[e], d2 = ei[NE + e];
  for (int i = t; i < 800; i += 256)
    fsum[i] = fm[(size_t)s * 800 + i] + fm[(size_t)d2 * 800 + i];
  if (t < 32) wsum[t] = awb[s * 64 + t] + awb[d2 * 64 + 32 + t];
  __syncthreads();
  if (t < 25) {
    float a = 0.f;
#pragma unroll
    for (int d = 0; d < 32; d++) a += wsum[d] * fsum[d * NSH + t];
    gl[t] = a;
  }
  __syncthreads();
  if (t < 196) {
    float a = 0.f;
#pragma unroll
    for (int m = 0; m < 25; m++) a += gl[m] * EXPc[m * 196 + t];
    out[HII_SZ + (size_t)e * 196 + t] = a;
  }
}

// =====================================================================
extern "C" void kernel_launch(void* const* d_in, const int* in_sizes, int n_in,
                              void* d_out, int out_size, void* d_ws, size_t ws_size,
                              hipStream_t stream) {
  (void)in_sizes; (void)n_in; (void)out_size;
  if (ws_size < NEED_BYTES) return;

  const int*   z    = (const int*)d_in[0];
  const float* pos  = (const float*)d_in[1];
  const int*   ei   = (const int*)d_in[2];
  const int*   tptr = (const int*)d_in[4];
  const int*   sptr = (const int*)d_in[5];
  const float* embed= (const float*)d_in[6];
  const float* tT   = (const float*)d_in[7];
  const float* tH   = (const float*)d_in[8];
  const float* sW1  = (const float*)d_in[9];
  const float* sb1  = (const float*)d_in[10];
  const float* sW2  = (const float*)d_in[11];
  const float* sb2  = (const float*)d_in[12];
  const float* rW1  = (const float*)d_in[13];
  const float* rb1  = (const float*)d_in[14];
  const float* rW2  = (const float*)d_in[15];
  const float* rb2  = (const float*)d_in[16];
  const float* rW3  = (const float*)d_in[17];
  const float* rb3  = (const float*)d_in[18];
  const float* mixW = (const float*)d_in[19];
  const float* Wq   = (const float*)d_in[20];
  const float* Wk   = (const float*)d_in[21];
  const float* Wii  = (const float*)d_in[22];
  const float* Wij  = (const float*)d_in[23];
  const float* pii  = (const float*)d_in[24];
  const float* pij  = (const float*)d_in[25];

  float* ws = (float*)d_ws;
  float* CGd   = ws + OFF_CONSTS;
  float* EXPd  = CGd + 15625;
  float* LBNd  = CGd + 15625 + 4900;
  float* x     = ws + OFF_X;
  float* agg   = ws + OFF_AGG;
  float* att   = ws + OFF_ATT;
  float* x0    = ws + OFF_X0;
  float* nsc   = ws + OFF_NSC;
  float* qarr  = ws + OFF_Q;
  float* karr  = ws + OFF_K;
  float* rbf   = ws + OFF_RBF;
  float* sh    = ws + OFF_SH;
  float* Tkp   = ws + OFF_TK;
  float* wrad  = ws + OFF_WRAD;
  float* agg2  = ws + OFF_AGG2;
  float* att2  = ws + OFF_ATT2;
  float* logits = ws + OFF_SH;            // sh dead after qh_tk
  float* alphaA = ws + OFF_SH + 65536;
  float* fm     = ws + OFF_AGG;           // agg dead after layer loop
  float* awb    = ws + OFF_AGG + 819200;
  int* ibase   = (int*)(ws + OFF_INT);
  int* counts  = ibase;
  int* starts  = ibase + 1024;
  int* cursor  = ibase + 1024 + 1025;
  int* perm    = ibase + 1024 + 1025 + 1024;
  float* outp  = (float*)d_out;

  hipMemcpyAsync(CGd, qhc::g_hc.buf, 20557 * sizeof(float), hipMemcpyHostToDevice, stream);

  qh_geom<<<NE / 256, 256, 0, stream>>>(pos, ei, LBNd, rbf, sh);
  qh_tk<<<NE / 32, 256, 0, stream>>>(sh, CGd, Tkp);
  qh_nsc<<<NN, 128, 0, stream>>>(z, tptr, sptr, embed, tT, tH, sW1, sb1, sW2, sb2, nsc, x, x0);
  qh_zero<<<NN / 256, 256, 0, stream>>>(counts);
  qh_count<<<NE / 256, 256, 0, stream>>>(ei, counts);
  qh_scan<<<1, 1024, 0, stream>>>(counts, starts, cursor);
  qh_scatter<<<NE / 256, 256, 0, stream>>>(ei, cursor, perm);

  for (int l = 0; l < NLAY; l++) {
    qh_rad<<<NE / 16, 256, 0, stream>>>(rbf,
        rW1 + (size_t)l * 32 * 64, rb1 + (size_t)l * 64,
        rW2 + (size_t)l * 64 * 64, rb2 + (size_t)l * 64,
        rW3 + (size_t)l * 64 * 128, rb3 + (size_t)l * 128, wrad);
    qh_qk<<<NN, 256, 0, stream>>>(x0, Wq + (size_t)l * 16384, Wk + (size_t)l * 16384, qarr, karr);
    qh_logit<<<NE / 2, 256, 0, stream>>>(qarr, karr, ei, logits);
    qh_soft<<<NN, 64, 0, stream>>>(logits, starts, perm, alphaA);
    qh_msgatt<<<NN * 4, 256, 0, stream>>>(x, Tkp, wrad, alphaA, starts, perm, ei,
                                          agg, att, agg2, att2);
    qh_mixgemm<<<800, 256, 0, stream>>>(mixW + (size_t)l * 81920, agg, agg2);
    qh_gate<<<NN, 256, 0, stream>>>(agg, att, att2, x, x0);
  }

  qh_prep<<<NN, 256, 0, stream>>>(x, nsc, Wii, Wij, pii, pij, EXPd, fm, awb, outp);
  qh_fij2<<<NE, 256, 0, stream>>>(ei, fm, awb, EXPd, outp);
}

// Round 14
// 1205.745 us; speedup vs baseline: 1.3179x; 1.3179x over previous
//
#include <hip/hip_runtime.h>
#include <cstdint>
#include <cmath>
#include <cstddef>

// ---------------- problem constants ----------------
constexpr int NN   = 1024;     // nodes
constexpr int NE   = 16384;    // edges
constexpr int HSZ  = 128;      // hidden size
constexpr int NSH  = 25;       // spherical harmonics (l<=4)
constexpr int NRBF = 32;
constexpr int NLAY = 5;
constexpr int XSZ  = HSZ * NSH;   // 3200
constexpr int HII_SZ = NN * 196;  // 200704
constexpr int TKP  = 800;         // padded Tk row: 25 i-rows x 32 slots

// x/agg/att layout: [n][m][c]  (element (n,m,c) at n*3200 + m*128 + c)

// ---------------- ws layout (float offsets) ----------------
constexpr size_t OFF_CONSTS = 0;  // CG 15625 | EXP 4900 | logbinom 32  (20557, pad 20560)
constexpr size_t OFF_X    = 20560;
constexpr size_t OFF_AGG  = OFF_X    + (size_t)NN * XSZ;
constexpr size_t OFF_ATT  = OFF_AGG  + (size_t)NN * XSZ;
constexpr size_t OFF_X0   = OFF_ATT  + (size_t)NN * XSZ;
constexpr size_t OFF_NSC  = OFF_X0   + (size_t)NN * HSZ;
constexpr size_t OFF_Q    = OFF_NSC  + (size_t)NN * HSZ;
constexpr size_t OFF_K    = OFF_Q    + (size_t)NN * HSZ;
constexpr size_t OFF_RBF  = OFF_K    + (size_t)NN * HSZ;
constexpr size_t OFF_SH   = OFF_RBF  + (size_t)NE * NRBF;
constexpr size_t OFF_TK   = OFF_SH   + (size_t)NE * NSH;
constexpr size_t OFF_WRAD = OFF_TK   + (size_t)NE * TKP;   // padded Tk
constexpr size_t OFF_INT  = OFF_WRAD + (size_t)NE * HSZ;   // ints start here
constexpr size_t NEED_BYTES = OFF_INT * 4 + (size_t)(1024 + 1025 + 1024 + 16384) * 4;
// aliases: logits->OFF_SH (65536) | alpha->OFF_SH+65536 | fm->OFF_AGG | awb->OFF_AGG+819200

// =====================================================================
// Host-side reproduction of np.random.default_rng(7) (verified round 3).
// =====================================================================
namespace qhc {

struct Pcg64 {
  unsigned __int128 state, inc;
  static unsigned __int128 mult() {
    return (((unsigned __int128)2549297995355413924ULL) << 64) | 4865540595714422341ULL;
  }
  void step() { state = state * mult() + inc; }
  uint64_t next64() {
    step();
    uint64_t hi = (uint64_t)(state >> 64), lo = (uint64_t)state;
    uint64_t x = hi ^ lo;
    unsigned rot = (unsigned)(state >> 122);
    return (x >> rot) | (x << ((64u - rot) & 63u));
  }
  double nextd() { return (double)(next64() >> 11) * (1.0 / 9007199254740992.0); }
};

struct HostConsts {
  float buf[20560];
  HostConsts() {
    const uint32_t INIT_A = 0x43b0d7e5u, MULT_A = 0x931e8875u;
    const uint32_t INIT_B = 0x8b51f9ddu, MULT_B = 0x58f38dedu;
    uint32_t pool[4];
    uint32_t hc = INIT_A;
    auto hashf = [&](uint32_t v) -> uint32_t {
      v ^= hc; hc *= MULT_A; v *= hc; v ^= v >> 16; return v;
    };
    auto mixf = [](uint32_t x, uint32_t y) -> uint32_t {
      uint32_t r = x * 0xca01f9ddu - y * 0x4973f715u;
      r ^= r >> 16;
      return r;
    };
    pool[0] = hashf(7u);
    for (int i = 1; i < 4; i++) pool[i] = hashf(0u);
    for (int s = 0; s < 4; s++)
      for (int d = 0; d < 4; d++)
        if (s != d) pool[d] = mixf(pool[d], hashf(pool[s]));
    uint32_t st32[8];
    uint32_t hb = INIT_B;
    for (int i = 0; i < 8; i++) {
      uint32_t v = pool[i % 4];
      v ^= hb; hb *= MULT_B; v *= hb; v ^= v >> 16;
      st32[i] = v;
    }
    uint64_t w0 = st32[0] | ((uint64_t)st32[1] << 32);
    uint64_t w1 = st32[2] | ((uint64_t)st32[3] << 32);
    uint64_t w2 = st32[4] | ((uint64_t)st32[5] << 32);
    uint64_t w3 = st32[6] | ((uint64_t)st32[7] << 32);
    unsigned __int128 seed = (((unsigned __int128)w0) << 64) | w1;
    unsigned __int128 incs = (((unsigned __int128)w2) << 64) | w3;
    Pcg64 g;
    g.state = 0; g.inc = (incs << 1) | 1;
    g.step(); g.state += seed; g.step();
    double wi[256], fi[256]; uint64_t ki[256];
    {
      const double m1 = 4503599627370496.0;
      double dn = 3.6541528853610087963519472518, tn = dn, vn = 0.00492867323399941;
      double q = vn / std::exp(-0.5 * dn * dn);
      ki[0] = (uint64_t)((dn / q) * m1); ki[1] = 0;
      wi[0] = q / m1; wi[255] = dn / m1;
      fi[0] = 1.0; fi[255] = std::exp(-0.5 * dn * dn);
      for (int i = 254; i >= 1; i--) {
        dn = std::sqrt(-2.0 * std::log(vn / dn + std::exp(-0.5 * dn * dn)));
        ki[i + 1] = (uint64_t)((dn / tn) * m1);
        tn = dn;
        fi[i] = std::exp(-0.5 * dn * dn);
        wi[i] = dn / m1;
      }
    }
    const double ZR = 3.6541528853610087963519472518;
    const double ZIR = 0.27366123732975827203338247596;
    auto stdnorm = [&]() -> double {
      for (;;) {
        uint64_t r = g.next64();
        int idx = (int)(r & 0xff);
        r >>= 8;
        int sign = (int)(r & 1);
        uint64_t rabs = (r >> 1) & 0x000fffffffffffffULL;
        double xv = (double)rabs * wi[idx];
        if (sign) xv = -xv;
        if (rabs < ki[idx]) return xv;
        if (idx == 0) {
          for (;;) {
            double xx = -ZIR * std::log1p(-g.nextd());
            double yy = -std::log1p(-g.nextd());
            if (yy + yy > xx * xx)
              return ((rabs >> 8) & 1) ? -(ZR + xx) : (ZR + xx);
          }
        } else {
          if (((fi[idx - 1] - fi[idx]) * g.nextd() + fi[idx]) < std::exp(-0.5 * xv * xv))
            return xv;
        }
      }
    };
    for (int i = 0; i < 15625 + 4900; i++) buf[i] = (float)(0.1 * stdnorm());
    double logf[32]; logf[0] = 0.0;
    for (int i = 1; i < 32; i++) logf[i] = logf[i - 1] + std::log((double)i);
    for (int k = 0; k < 32; k++) buf[15625 + 4900 + k] = (float)(logf[31] - logf[k] - logf[31 - k]);
    buf[20557] = buf[20558] = buf[20559] = 0.f;
  }
};
static HostConsts g_hc;
}  // namespace qhc

// =====================================================================
__device__ __forceinline__ float siluf(float a) { return a / (1.f + expf(-a)); }

// ---------------- edge geometry: sh + rbf ----------------
__global__ __launch_bounds__(256) void qh_geom(
    const float* __restrict__ pos, const int* __restrict__ ei,
    const float* __restrict__ lbn, float* __restrict__ rbf, float* __restrict__ sh) {
  int e = blockIdx.x * 256 + threadIdx.x;
  if (e >= NE) return;
  int s = ei[e], d = ei[NE + e];
  float vx = pos[s * 3 + 0] - pos[d * 3 + 0];
  float vy = pos[s * 3 + 1] - pos[d * 3 + 1];
  float vz = pos[s * 3 + 2] - pos[d * 3 + 2];
  float r = sqrtf(vx * vx + vy * vy + vz * vz + 1e-12f);
  float inv = 1.0f / r;
  float x = vx * inv, y = vy * inv, z = vz * inv;
  float x2 = x * x, y2 = y * y, z2 = z * z;
  float* sp = sh + (size_t)e * NSH;
  sp[0] = 0.282095f;
  sp[1] = 0.488603f * y;
  sp[2] = 0.488603f * z;
  sp[3] = 0.488603f * x;
  sp[4] = 1.092548f * x * y;
  sp[5] = 1.092548f * y * z;
  sp[6] = 0.315392f * (3.f * z2 - 1.f);
  sp[7] = 1.092548f * x * z;
  sp[8] = 0.546274f * (x2 - y2);
  sp[9] = 0.590044f * y * (3.f * x2 - y2);
  sp[10] = 2.890611f * x * y * z;
  sp[11] = 0.457046f * y * (5.f * z2 - 1.f);
  sp[12] = 0.373176f * z * (5.f * z2 - 3.f);
  sp[13] = 0.457046f * x * (5.f * z2 - 1.f);
  sp[14] = 1.445306f * z * (x2 - y2);
  sp[15] = 0.590044f * x * (x2 - 3.f * y2);
  sp[16] = 2.503343f * x * y * (x2 - y2);
  sp[17] = 1.770131f * y * z * (3.f * x2 - y2);
  sp[18] = 0.946175f * x * y * (7.f * z2 - 1.f);
  sp[19] = 0.669047f * y * z * (7.f * z2 - 3.f);
  sp[20] = 0.105786f * (35.f * z2 * z2 - 30.f * z2 + 3.f);
  sp[21] = 0.669047f * x * z * (7.f * z2 - 3.f);
  sp[22] = 0.473087f * (x2 - y2) * (7.f * z2 - 1.f);
  sp[23] = 1.770131f * x * z * (x2 - 3.f * y2);
  sp[24] = 0.625836f * (x2 * x2 - 6.f * x2 * y2 + y2 * y2);
  float xr = expf(-0.5f * r);
  float l1 = log1pf(-xr + 1e-7f);
  float fc = 0.5f * (cosf(3.14159265358979323846f * fminf(r * (1.0f / 12.0f), 1.0f)) + 1.0f);
  float* rp = rbf + (size_t)e * NRBF;
  for (int k = 0; k < NRBF; k++) {
    float b = expf(lbn[k] + (float)k * (-0.5f * r) + (float)(NRBF - 1 - k) * l1);
    rp[k] = b * fc;
  }
}

// ---------------- Tkp[e][i][32] (padded, wave-group-aligned) ----------------
// Tk value (i,k) at slot i*32 + k + (k>=7) + 2*(k>=13) + 2*(k>=19):
// groups of 8 slots at {0,8,16,24} hold k-ranges {0-6},{7-12},{13-18},{19-24},
// pad slots zeroed. Built ONCE here instead of per-msgatt-block in LDS.
__global__ __launch_bounds__(256) void qh_tk(
    const float* __restrict__ sh, const float* __restrict__ CG, float* __restrict__ Tkp) {
  __shared__ float shl[32 * NSH];
  int e0 = blockIdx.x * 32;
  int t = threadIdx.x;
  for (int i = t; i < 32 * NSH; i += 256) shl[i] = sh[(size_t)e0 * NSH + i];
  // zero all slots; value slots overwritten after the barrier
  for (int i = t; i < 32 * TKP; i += 256) Tkp[(size_t)e0 * TKP + i] = 0.f;
  __syncthreads();
  for (int ik = t; ik < NSH * NSH; ik += 256) {
    int i = ik / NSH, k = ik % NSH;
    int pos = i * 32 + k + (k >= 7) + 2 * (k >= 13) + 2 * (k >= 19);
    float cg[NSH];
#pragma unroll
    for (int j = 0; j < NSH; j++) cg[j] = CG[i * 625 + j * NSH + k];
    for (int ee = 0; ee < 32; ee++) {
      float acc = 0.f;
#pragma unroll
      for (int j = 0; j < NSH; j++) acc += shl[ee * NSH + j] * cg[j];
      Tkp[(size_t)(e0 + ee) * TKP + pos] = acc;
    }
  }
}

// ---------------- node scalar MLP + init x ([m][c] layout) ----------------
__global__ __launch_bounds__(128) void qh_nsc(
    const int* __restrict__ z, const int* __restrict__ tptr, const int* __restrict__ sptr,
    const float* __restrict__ embed, const float* __restrict__ tT, const float* __restrict__ tH,
    const float* __restrict__ W1, const float* __restrict__ b1,
    const float* __restrict__ W2, const float* __restrict__ b2,
    float* __restrict__ nsc, float* __restrict__ x, float* __restrict__ x0) {
  __shared__ float cat[384];
  __shared__ float h[128];
  int nd = blockIdx.x, d = threadIdx.x;
  int zz = z[nd], tt = tptr[0], st = sptr[0];
  cat[d] = embed[zz * HSZ + d];
  cat[128 + d] = tT[tt * HSZ + d];
  cat[256 + d] = tH[st * HSZ + d];
  __syncthreads();
  float a = b1[d];
  for (int c = 0; c < 384; c++) a += cat[c] * W1[c * HSZ + d];
  h[d] = fmaxf(a, 0.f);
  __syncthreads();
  a = b2[d];
  for (int c = 0; c < 128; c++) a += h[c] * W2[c * HSZ + d];
  nsc[nd * HSZ + d] = a;
  x0[nd * HSZ + d] = a;
  float* xr = x + (size_t)nd * XSZ + d;
  xr[0] = a;                       // m=0
  for (int m = 1; m < NSH; m++) xr[m * 128] = 0.f;
}

// ---------------- dst-bucket sort ----------------
__global__ __launch_bounds__(256) void qh_zero(int* counts) {
  int i = blockIdx.x * 256 + threadIdx.x;
  if (i < NN) counts[i] = 0;
}
__global__ __launch_bounds__(256) void qh_count(const int* __restrict__ ei, int* counts) {
  int e = blockIdx.x * 256 + threadIdx.x;
  if (e < NE) atomicAdd(&counts[ei[NE + e]], 1);
}
__global__ __launch_bounds__(1024) void qh_scan(const int* __restrict__ counts,
                                                int* starts, int* cursor) {
  __shared__ int tmp[NN];
  int t = threadIdx.x;
  tmp[t] = counts[t];
  __syncthreads();
  for (int ofs = 1; ofs < NN; ofs <<= 1) {
    int v = (t >= ofs) ? tmp[t - ofs] : 0;
    __syncthreads();
    tmp[t] += v;
    __syncthreads();
  }
  starts[t + 1] = tmp[t];
  if (t == 0) starts[0] = 0;
  cursor[t] = (t == 0) ? 0 : tmp[t - 1];
}
__global__ __launch_bounds__(256) void qh_scatter(const int* __restrict__ ei,
                                                  int* cursor, int* perm) {
  int e = blockIdx.x * 256 + threadIdx.x;
  if (e < NE) {
    int d = ei[NE + e];
    int pos = atomicAdd(&cursor[d], 1);
    perm[pos] = e;
  }
}

// ---------------- radial MLP: 16 edges/block, 4-edge-parallel phases ----------------
__global__ __launch_bounds__(256) void qh_rad(
    const float* __restrict__ rbf,
    const float* __restrict__ W1, const float* __restrict__ b1,
    const float* __restrict__ W2, const float* __restrict__ b2,
    const float* __restrict__ W3, const float* __restrict__ b3,
    float* __restrict__ wrad) {
  __shared__ float w1l[2048], w2l[4096], w3l[8192];
  __shared__ float rl[4][32], h1[4][64], h2[4][64];
  int t = threadIdx.x;
  for (int i = t; i < 2048; i += 256) w1l[i] = W1[i];
  for (int i = t; i < 4096; i += 256) w2l[i] = W2[i];
  for (int i = t; i < 8192; i += 256) w3l[i] = W3[i];
  __syncthreads();
  int e0 = blockIdx.x * 16;
  for (int q = 0; q < 4; q++) {
    int eb = e0 + q * 4;
    if (t < 128) rl[t >> 5][t & 31] = rbf[(size_t)(eb + (t >> 5)) * NRBF + (t & 31)];
    __syncthreads();
    {
      int eg = t >> 6, u = t & 63;
      float a = b1[u];
      for (int c = 0; c < 32; c++) a += rl[eg][c] * w1l[c * 64 + u];
      h1[eg][u] = siluf(a);
    }
    __syncthreads();
    {
      int eg = t >> 6, u = t & 63;
      float a = b2[u];
      for (int c = 0; c < 64; c++) a += h1[eg][c] * w2l[c * 64 + u];
      h2[eg][u] = siluf(a);
    }
    __syncthreads();
#pragma unroll
    for (int p = 0; p < 2; p++) {
      int eg = (t >> 7) + p * 2, u = t & 127;
      float a = b3[u];
      for (int c = 0; c < 64; c++) a += h2[eg][c] * w3l[c * 128 + u];
      wrad[(size_t)(eb + eg) * HSZ + u] = a;
    }
    __syncthreads();
  }
}

// ---------------- q/k projections ----------------
__global__ __launch_bounds__(256) void qh_qk(
    const float* __restrict__ x0, const float* __restrict__ Wq, const float* __restrict__ Wk,
    float* __restrict__ q, float* __restrict__ kk) {
  __shared__ float xl[128];
  int nd = blockIdx.x, t = threadIdx.x;
  if (t < 128) xl[t] = x0[nd * HSZ + t];
  __syncthreads();
  int d = t & 127;
  const float* W = (t < 128) ? Wq : Wk;
  float a = 0.f;
  for (int c = 0; c < 128; c++) a += xl[c] * W[c * HSZ + d];
  if (t < 128) q[nd * HSZ + d] = a;
  else kk[nd * HSZ + d] = a;
}

// ---------------- edge-parallel attention logits ----------------
__global__ __launch_bounds__(256) void qh_logit(
    const float* __restrict__ q, const float* __restrict__ kk,
    const int* __restrict__ ei, float* __restrict__ logits) {
  int t = threadIdx.x;
  int e = blockIdx.x * 2 + (t >> 7);
  int c = t & 127;
  int s = ei[e], d = ei[NE + e];
  float p = q[d * HSZ + c] * kk[s * HSZ + c];
#pragma unroll
  for (int m = 16; m >= 1; m >>= 1) p += __shfl_xor(p, m);
  if ((c & 31) == 0) logits[e * 4 + (c >> 5)] = p * 0.17677669529663687f;
}

// ---------------- per-node exact softmax (16 lanes per head) ----------------
__global__ __launch_bounds__(64) void qh_soft(
    const float* __restrict__ logits, const int* __restrict__ starts,
    const int* __restrict__ perm, float* __restrict__ alpha) {
  int nd = blockIdx.x, t = threadIdx.x;
  int hh = t >> 4, l = t & 15;
  int jb = starts[nd], je = starts[nd + 1];
  float m = -1e30f;
  for (int j = jb + l; j < je; j += 16) m = fmaxf(m, logits[perm[j] * 4 + hh]);
#pragma unroll
  for (int s = 1; s < 16; s <<= 1) m = fmaxf(m, __shfl_xor(m, s));
  float den = 0.f;
  for (int j = jb + l; j < je; j += 16) den += expf(logits[perm[j] * 4 + hh] - m);
#pragma unroll
  for (int s = 1; s < 16; s <<= 1) den += __shfl_xor(den, s);
  float inv = 1.f / (den + 1e-9f);
  for (int j = jb + l; j < je; j += 16) {
    int e = perm[j];
    alpha[e * 4 + hh] = expf(logits[e * 4 + hh] - m) * inv;
  }
}

// ---------------- fused message + attention agg (r10 + float4 staging) ------------
// Best-known msgatt (r12: ~106.5 us, FETCH ~146 MB, VGPR 28, occ ~54%).
// XCD-pairing swizzle (both half-blocks of a node share bid%8 -> same L2),
// wave-uniform s_load Tk path, float4 x staging. r13's 2-chunk split REVERTED:
// it doubled WRITE_SIZE (agg2/att2 round-trip) and per-block fixed costs and
// regressed 106->181 us despite higher occupancy.
__global__ __launch_bounds__(256, 8) void qh_msgatt(
    const float* __restrict__ x, const float* __restrict__ Tkp,
    const float* __restrict__ wrad, const float* __restrict__ alpha,
    const int* __restrict__ starts, const int* __restrict__ perm,
    const int* __restrict__ ei,
    float* __restrict__ agg, float* __restrict__ att) {
  __shared__ __align__(16) float xs[2][1600];   // [m][cl] 25 x 64
  __shared__ float wl[2][64];
  int bid = blockIdx.x;
  int nd = (bid >> 4) * 8 + (bid & 7);          // XCD-pairing swizzle
  int h  = (bid >> 3) & 1;
  int t = threadIdx.x;
  int cl = t & 63, q4 = t >> 6;
  int q4u = __builtin_amdgcn_readfirstlane(q4);   // wave id -> SGPR
  int c = h * 64 + cl;
  int k0 = (q4 == 0) ? 0 : (1 + 6 * q4); // {0,7,13,19}
  int nk = (q4 == 0) ? 7 : 6;
  float am[7], aa[7];
#pragma unroll
  for (int u = 0; u < 7; u++) { am[u] = 0.f; aa[u] = 0.f; }
  int jb = starts[nd], je = starts[nd + 1];

  float4 rxA = {0, 0, 0, 0}, rxB = {0, 0, 0, 0};
  float rw = 0.f;
  if (jb < je) {
    int e = perm[jb], s = ei[e];
    const float* xb0 = x + (size_t)s * XSZ + h * 64;
    rxA = *(const float4*)(xb0 + (t >> 4) * 128 + (t & 15) * 4);
    if (t < 144) rxB = *(const float4*)(xb0 + ((256 + t) >> 4) * 128 + (t & 15) * 4);
    if (t < 64) rw = wrad[(size_t)e * HSZ + h * 64 + t];
    ((float4*)xs[0])[t] = rxA;
    if (t < 144) ((float4*)xs[0])[256 + t] = rxB;
    if (t < 64) wl[0][t] = rw;
  }
  __syncthreads();
  for (int j = jb; j < je; j++) {
    int cur = (j - jb) & 1, nxt = cur ^ 1;
    int e = perm[j];
    int eu = __builtin_amdgcn_readfirstlane(e);   // uniform edge id -> SGPR
    const float* tkr = Tkp + (size_t)eu * TKP + q4u * 8;  // all-scalar address
    float al = alpha[e * 4 + (c >> 5)];
    bool more = (j + 1 < je);
    if (more) {  // register prefetch of next edge's x/wrad overlaps compute
      int e2 = perm[j + 1], s2 = ei[e2];
      const float* xb2 = x + (size_t)s2 * XSZ + h * 64;
      rxA = *(const float4*)(xb2 + (t >> 4) * 128 + (t & 15) * 4);
      if (t < 144) rxB = *(const float4*)(xb2 + ((256 + t) >> 4) * 128 + (t & 15) * 4);
      if (t < 64) rw = wrad[(size_t)e2 * HSZ + h * 64 + t];
    }
    float wc = wl[cur][cl];
#pragma unroll 5
    for (int i = 0; i < NSH; i++) {
      float xw = xs[cur][i * 64 + cl] * wc;
      float4 t0 = *(const float4*)(tkr + i * 32);       // wave-uniform 16B
      float4 t1 = *(const float4*)(tkr + i * 32 + 4);   // wave-uniform 16B
      am[0] += xw * t0.x; am[1] += xw * t0.y; am[2] += xw * t0.z; am[3] += xw * t0.w;
      am[4] += xw * t1.x; am[5] += xw * t1.y; am[6] += xw * t1.z;
    }
#pragma unroll
    for (int u = 0; u < 7; u++)
      if (u < nk) aa[u] += al * xs[cur][(k0 + u) * 64 + cl];
    __syncthreads();
    if (more) {
      ((float4*)xs[nxt])[t] = rxA;
      if (t < 144) ((float4*)xs[nxt])[256 + t] = rxB;
      if (t < 64) wl[nxt][t] = rw;
    }
    __syncthreads();
  }
#pragma unroll
  for (int u = 0; u < 7; u++)
    if (u < nk) {
      agg[(size_t)nd * XSZ + (k0 + u) * 128 + c] = am[u];
      att[(size_t)nd * XSZ + (k0 + u) * 128 + c] = aa[u];
    }
}

// ---------------- mix as row-GEMM: agg[row] <- agg[row] @ W_lb (in place) ----------------
// 800 blocks: per-lb row tiles of 32 (rows exclusive per block -> in-place safe).
// Full-width tile — 16 outputs/thread (4 rows x 4 d via float4 Wl), one pass
// over the whole 128-d width. Per cc: 4 Al b32 + 1 Wl b128 = 5 LDS instrs /
// 16 outputs. Wl = whole [128cc][128d] tile (64 KB); LDS total 80 KB ->
// 2 blocks/CU. One barrier. In-place safe: Al fully read before any write.
__global__ __launch_bounds__(256) void qh_mixgemm(
    const float* __restrict__ mixW, float* __restrict__ agg) {
  __shared__ __align__(16) float Wl[16384];  // [cc][128], 64 KB
  __shared__ __align__(16) float Al[4096];   // [32 rows][128 cc], 16 KB
  int b = blockIdx.x, t = threadIdx.x;
  int lb, cum;
  if (b < 32)       { lb = 0; cum = 0; }
  else if (b < 128) { lb = 1; cum = 32; }
  else if (b < 288) { lb = 2; cum = 128; }
  else if (b < 512) { lb = 3; cum = 288; }
  else              { lb = 4; cum = 512; }
  int sl = 2 * lb + 1, o = lb * lb;
  int row0 = (b - cum) * 32;
  const float* W = mixW + lb * 16384;
  // Al staging: 1024 float4 (each row is 32 float4s)
  for (int i = t; i < 1024; i += 256) {
    int r = i >> 5, c4 = (i & 31) * 4;
    int gr = row0 + r, n = gr / sl, m = o + gr - n * sl;
    *(float4*)&Al[r * 128 + c4] =
        *(const float4*)&agg[(size_t)n * XSZ + m * 128 + c4];
  }
  // Wl staging: linear copy of the whole [128][128] tile (4096 float4)
  for (int i = t; i < 4096; i += 256)
    *(float4*)&Wl[i * 4] = *(const float4*)&W[i * 4];
  __syncthreads();
  int d4 = (t & 31) * 4;   // 4 consecutive d
  int rg = t >> 5;         // 8 groups x 4 rows
  float acc[4][4];
#pragma unroll
  for (int r = 0; r < 4; r++)
#pragma unroll
    for (int q = 0; q < 4; q++) acc[r][q] = 0.f;
  for (int cc = 0; cc < 128; cc++) {
    float4 w4 = *(const float4*)&Wl[cc * 128 + d4];
#pragma unroll
    for (int r = 0; r < 4; r++) {
      float a = Al[(rg * 4 + r) * 128 + cc];
      acc[r][0] += a * w4.x; acc[r][1] += a * w4.y;
      acc[r][2] += a * w4.z; acc[r][3] += a * w4.w;
    }
  }
#pragma unroll
  for (int r = 0; r < 4; r++) {
    int gr = row0 + rg * 4 + r, n = gr / sl, m = o + gr - n * sl;
    float4 v; v.x = acc[r][0]; v.y = acc[r][1]; v.z = acc[r][2]; v.w = acc[r][3];
    *(float4*)&agg[(size_t)n * XSZ + m * 128 + d4] = v;
  }
}

// ---------------- gate epilogue: x = gate(x + y + att) ----------------
__global__ __launch_bounds__(256) void qh_gate(
    const float* __restrict__ y, const float* __restrict__ att,
    float* __restrict__ x, float* __restrict__ x0) {
  __shared__ float v0l[128];
  int nd = blockIdx.x, t = threadIdx.x;
  int d = t & 127, mh = t >> 7;
  int m0 = mh ? 13 : 0, nm = mh ? 12 : 13;
  float v[13];
  size_t base = (size_t)nd * XSZ + (size_t)m0 * 128 + d;
#pragma unroll
  for (int u = 0; u < 13; u++)
    if (u < nm) v[u] = x[base + (size_t)u * 128] + y[base + (size_t)u * 128] + att[base + (size_t)u * 128];
  if (mh == 0) v0l[d] = v[0];
  __syncthreads();
  float g = 1.f / (1.f + expf(-v0l[d]));
#pragma unroll
  for (int u = 0; u < 13; u++)
    if (u < nm) x[base + (size_t)u * 128] = v[u] * g;   // m=0: v0*g == silu(v0)
  if (mh == 0) x0[nd * HSZ + d] = v[0] * g;
}

// ---------------- per-node output precompute + H_ii ----------------
__global__ __launch_bounds__(256) void qh_prep(
    const float* __restrict__ x, const float* __restrict__ nsc,
    const float* __restrict__ Wii, const float* __restrict__ Wij,
    const float* __restrict__ pii, const float* __restrict__ pij,
    const float* __restrict__ EXPc,
    float* __restrict__ fm, float* __restrict__ awb, float* __restrict__ out) {
  __shared__ float xl[XSZ];
  __shared__ float nl[128];
  __shared__ float wc[4096];
  __shared__ float fml[800];
  __shared__ float wiil[32];
  __shared__ float gl[25];
  int nd = blockIdx.x, t = threadIdx.x;
  for (int i = t; i < XSZ; i += 256) xl[i] = x[(size_t)nd * XSZ + i];
  if (t < 128) nl[t] = nsc[nd * HSZ + t];
  __syncthreads();
  if (t < 32) {
    float a = 0.f;
    for (int cc = 0; cc < 128; cc++) a += nl[cc] * pii[cc * 32 + t];
    wiil[t] = a;
  } else if (t < 96) {
    int d = (t - 32) & 31;
    int half = (t - 32) >> 5;
    const float* pp = pij + (half ? 128 * 32 : 0);
    float a = 0.f;
    for (int cc = 0; cc < 128; cc++) a += nl[cc] * pp[cc * 32 + d];
    awb[nd * 64 + half * 32 + d] = a;
  }
  for (int lb = 0; lb < 5; lb++) {
    __syncthreads();
    for (int i = t; i < 4096; i += 256) wc[i] = Wii[lb * 4096 + i];
    __syncthreads();
    int o = lb * lb, sl = 2 * lb + 1;
    for (int idx = t; idx < 32 * sl; idx += 256) {
      int d = idx & 31, m = o + (idx >> 5);
      float a = 0.f;
      for (int cc = 0; cc < 128; cc++) a += xl[m * 128 + cc] * wc[cc * 32 + d];
      fml[d * NSH + m] = a;
    }
  }
  __syncthreads();
  if (t < 25) {
    float a = 0.f;
#pragma unroll
    for (int d = 0; d < 32; d++) a += wiil[d] * fml[d * NSH + t];
    gl[t] = a;
  }
  __syncthreads();
  if (t < 196) {
    float a = 0.f;
#pragma unroll
    for (int m = 0; m < 25; m++) a += gl[m] * EXPc[m * 196 + t];
    out[(size_t)nd * 196 + t] = a;
  }
  for (int lb = 0; lb < 5; lb++) {
    __syncthreads();
    for (int i = t; i < 4096; i += 256) wc[i] = Wij[lb * 4096 + i];
    __syncthreads();
    int o = lb * lb, sl = 2 * lb + 1;
    for (int idx = t; idx < 32 * sl; idx += 256) {
      int d = idx & 31, m = o + (idx >> 5);
      float a = 0.f;
      for (int cc = 0; cc < 128; cc++) a += xl[m * 128 + cc] * wc[cc * 32 + d];
      fm[(size_t)nd * 800 + d * NSH + m] = a;
    }
  }
}

// ---------------- H_ij per edge (factorized) ----------------
__global__ __launch_bounds__(256) void qh_fij2(
    const int* __restrict__ ei, const float* __restrict__ fm,
    const float* __restrict__ awb, const float* __restrict__ EXPc,
    float* __restrict__ out) {
  __shared__ float fsum[800], wsum[32], gl[25];
  int e = blockIdx.x, t = threadIdx.x;
  int s = ei[e], d2 = ei[NE + e];
  for (int i = t; i < 800; i += 256)
    fsum[i] = fm[(size_t)s * 800 + i] + fm[(size_t)d2 * 800 + i];
  if (t < 32) wsum[t] = awb[s * 64 + t] + awb[d2 * 64 + 32 + t];
  __syncthreads();
  if (t < 25) {
    float a = 0.f;
#pragma unroll
    for (int d = 0; d < 32; d++) a += wsum[d] * fsum[d * NSH + t];
    gl[t] = a;
  }
  __syncthreads();
  if (t < 196) {
    float a = 0.f;
#pragma unroll
    for (int m = 0; m < 25; m++) a += gl[m] * EXPc[m * 196 + t];
    out[HII_SZ + (size_t)e * 196 + t] = a;
  }
}

// =====================================================================
extern "C" void kernel_launch(void* const* d_in, const int* in_sizes, int n_in,
                              void* d_out, int out_size, void* d_ws, size_t ws_size,
                              hipStream_t stream) {
  (void)in_sizes; (void)n_in; (void)out_size;
  if (ws_size < NEED_BYTES) return;

  const int*   z    = (const int*)d_in[0];
  const float* pos  = (const float*)d_in[1];
  const int*   ei   = (const int*)d_in[2];
  const int*   tptr = (const int*)d_in[4];
  const int*   sptr = (const int*)d_in[5];
  const float* embed= (const float*)d_in[6];
  const float* tT   = (const float*)d_in[7];
  const float* tH   = (const float*)d_in[8];
  const float* sW1  = (const float*)d_in[9];
  const float* sb1  = (const float*)d_in[10];
  const float* sW2  = (const float*)d_in[11];
  const float* sb2  = (const float*)d_in[12];
  const float* rW1  = (const float*)d_in[13];
  const float* rb1  = (const float*)d_in[14];
  const float* rW2  = (const float*)d_in[15];
  const float* rb2  = (const float*)d_in[16];
  const float* rW3  = (const float*)d_in[17];
  const float* rb3  = (const float*)d_in[18];
  const float* mixW = (const float*)d_in[19];
  const float* Wq   = (const float*)d_in[20];
  const float* Wk   = (const float*)d_in[21];
  const float* Wii  = (const float*)d_in[22];
  const float* Wij  = (const float*)d_in[23];
  const float* pii  = (const float*)d_in[24];
  const float* pij  = (const float*)d_in[25];

  float* ws = (float*)d_ws;
  float* CGd   = ws + OFF_CONSTS;
  float* EXPd  = CGd + 15625;
  float* LBNd  = CGd + 15625 + 4900;
  float* x     = ws + OFF_X;
  float* agg   = ws + OFF_AGG;
  float* att   = ws + OFF_ATT;
  float* x0    = ws + OFF_X0;
  float* nsc   = ws + OFF_NSC;
  float* qarr  = ws + OFF_Q;
  float* karr  = ws + OFF_K;
  float* rbf   = ws + OFF_RBF;
  float* sh    = ws + OFF_SH;
  float* Tkp   = ws + OFF_TK;
  float* wrad  = ws + OFF_WRAD;
  float* logits = ws + OFF_SH;            // sh dead after qh_tk
  float* alphaA = ws + OFF_SH + 65536;
  float* fm     = ws + OFF_AGG;           // agg dead after layer loop
  float* awb    = ws + OFF_AGG + 819200;
  int* ibase   = (int*)(ws + OFF_INT);
  int* counts  = ibase;
  int* starts  = ibase + 1024;
  int* cursor  = ibase + 1024 + 1025;
  int* perm    = ibase + 1024 + 1025 + 1024;
  float* outp  = (float*)d_out;

  hipMemcpyAsync(CGd, qhc::g_hc.buf, 20557 * sizeof(float), hipMemcpyHostToDevice, stream);

  qh_geom<<<NE / 256, 256, 0, stream>>>(pos, ei, LBNd, rbf, sh);
  qh_tk<<<NE / 32, 256, 0, stream>>>(sh, CGd, Tkp);
  qh_nsc<<<NN, 128, 0, stream>>>(z, tptr, sptr, embed, tT, tH, sW1, sb1, sW2, sb2, nsc, x, x0);
  qh_zero<<<NN / 256, 256, 0, stream>>>(counts);
  qh_count<<<NE / 256, 256, 0, stream>>>(ei, counts);
  qh_scan<<<1, 1024, 0, stream>>>(counts, starts, cursor);
  qh_scatter<<<NE / 256, 256, 0, stream>>>(ei, cursor, perm);

  for (int l = 0; l < NLAY; l++) {
    qh_rad<<<NE / 16, 256, 0, stream>>>(rbf,
        rW1 + (size_t)l * 32 * 64, rb1 + (size_t)l * 64,
        rW2 + (size_t)l * 64 * 64, rb2 + (size_t)l * 64,
        rW3 + (size_t)l * 64 * 128, rb3 + (size_t)l * 128, wrad);
    qh_qk<<<NN, 256, 0, stream>>>(x0, Wq + (size_t)l * 16384, Wk + (size_t)l * 16384, qarr, karr);
    qh_logit<<<NE / 2, 256, 0, stream>>>(qarr, karr, ei, logits);
    qh_soft<<<NN, 64, 0, stream>>>(logits, starts, perm, alphaA);
    qh_msgatt<<<NN * 2, 256, 0, stream>>>(x, Tkp, wrad, alphaA, starts, perm, ei, agg, att);
    qh_mixgemm<<<800, 256, 0, stream>>>(mixW + (size_t)l * 81920, agg);
    qh_gate<<<NN, 256, 0, stream>>>(agg, att, x, x0);
  }

  qh_prep<<<NN, 256, 0, stream>>>(x, nsc, Wii, Wij, pii, pij, EXPd, fm, awb, outp);
  qh_fij2<<<NE, 256, 0, stream>>>(ei, fm, awb, EXPd, outp);
}